// Round 8
// baseline (359.518 us; speedup 1.0000x reference)
//
#include <hip/hip_runtime.h>
#include <hip/hip_bf16.h>

#define NPX 16384
typedef __attribute__((ext_vector_type(8))) short short8;
typedef __attribute__((ext_vector_type(4))) short short4v;
typedef __attribute__((ext_vector_type(8))) _Float16 half8;
typedef __attribute__((ext_vector_type(4))) _Float16 half4;
typedef __attribute__((ext_vector_type(4))) float f32x4;

#define DEV static __device__ __forceinline__

// wt layout (fp16 shorts)
#define WAB   0
#define WINW  4096
#define W1T   8192
#define W2T   16384
#define W3T   32768
#define WQT   40960
#define WKV   45056
#define WTOT  53248

DEV float lrelu(float v) { return v >= 0.f ? v : 0.01f * v; }
DEV short f2h(float f) { _Float16 h = (_Float16)f; return __builtin_bit_cast(short, h); }
DEV float h2f(short s) { return (float)__builtin_bit_cast(_Float16, s); }
DEV f32x4 mfmah(half8 a, half8 b, f32x4 c) {
    return __builtin_amdgcn_mfma_f32_16x16x32_f16(a, b, c, 0, 0, 0);
}
DEV f32x4 mfmah16(half4 a, half4 b, f32x4 c) {
    return __builtin_amdgcn_mfma_f32_16x16x16f16(a, b, c, 0, 0, 0);
}

// ---------------------------------------------------------------------------
// Swapped-operand GEMM: acc[t] = W(A-op) x tile(B-op).
// D: lane ln -> px=ln ; reg r of tile t -> channel e = t*16 + (lane>>4)*4 + r
// tile LDS layout [px][ch] pitch (mult of 4); WT [e][K] global.
// ---------------------------------------------------------------------------
template<int K, int NT>
DEV void gemmT(const short* __restrict__ A, int pitch,
               const short* __restrict__ WT, f32x4 (&acc)[NT])
{
    int lane = threadIdx.x & 63;
    int ln = lane & 15, q8 = (lane >> 4) * 8;
    const short* bp = A + (size_t)ln * pitch + q8;
#pragma unroll
    for (int c0 = 0; c0 < K; c0 += 32) {
        half8 bfrag = *(const half8*)(bp + c0);
#pragma unroll
        for (int t = 0; t < NT; ++t) {
            half8 afrag = *(const half8*)(WT + (size_t)(t * 16 + ln) * K + q8 + c0);
            acc[t] = mfmah(afrag, bfrag, acc[t]);
        }
    }
}

// bias: e = t*16 + qd*4 + r  -> vector load
template<int NT>
DEV void acc_biasT(f32x4 (&acc)[NT], const float* __restrict__ bias)
{
    int qd4 = ((threadIdx.x & 63) >> 4) * 4;
#pragma unroll
    for (int t = 0; t < NT; ++t) acc[t] = *(const f32x4*)(bias + t * 16 + qd4);
}

// packed b64 store of D into [px][ch] tile
template<int NT>
DEV void dstoreT(const f32x4* acc, short* sD, int pitch)
{
    int lane = threadIdx.x & 63;
    int ln = lane & 15, qd4 = (lane >> 4) * 4;
#pragma unroll
    for (int t = 0; t < NT; ++t) {
        short4v pk = {f2h(acc[t][0]), f2h(acc[t][1]), f2h(acc[t][2]), f2h(acc[t][3])};
        *reinterpret_cast<short4v*>(&sD[ln * pitch + t * 16 + qd4]) = pk;
    }
}

// in-register LayerNorm(+lrelu) over 128 ch (per px=ln); 2 shuffles
template<int NT>
DEV void ln_T(f32x4 (&acc)[NT], const float* __restrict__ g, const float* __restrict__ be)
{
    int qd4 = ((threadIdx.x & 63) >> 4) * 4;
    float s = 0.f, ss = 0.f;
#pragma unroll
    for (int t = 0; t < NT; ++t)
#pragma unroll
        for (int r = 0; r < 4; ++r) { float v = acc[t][r]; s += v; ss += v * v; }
    s += __shfl_xor(s, 16); ss += __shfl_xor(ss, 16);
    s += __shfl_xor(s, 32); ss += __shfl_xor(ss, 32);
    float m = s * (1.f / 128.f);
    float var = ss * (1.f / 128.f) - m * m;
    float rs = rsqrtf(var + 1e-5f);
#pragma unroll
    for (int t = 0; t < NT; ++t) {
        f32x4 gg = *(const f32x4*)(g + t * 16 + qd4);
        f32x4 bb = *(const f32x4*)(be + t * 16 + qd4);
#pragma unroll
        for (int r = 0; r < 4; ++r)
            acc[t][r] = lrelu((acc[t][r] - m) * rs * gg[r] + bb[r]);
    }
}

// wave-level copyout of 16x64 fp16 tile -> global [px][64]
DEV void copyout16(const short* sD, int pitch, short* __restrict__ dst)
{
    int lane = threadIdx.x & 63;
#pragma unroll
    for (int it = 0; it < 2; ++it) {
        int idx = it * 512 + lane * 8;
        int px = idx >> 6, c = idx & 63;
        short8 v = *(const short8*)(&sD[px * pitch + c]);
        *reinterpret_cast<short8*>(dst + (size_t)px * 64 + c) = v;
    }
}

// stage 16 px of x (fp32 channel-major) -> wave LDS [16][72] fp16
DEV void stage_x16(const float* __restrict__ xb, int n0, short* X)
{
    int lane = threadIdx.x & 63;
    int ln = lane & 15, qd = lane >> 4;
    float vb[16];
#pragma unroll
    for (int t = 0; t < 16; ++t) vb[t] = xb[(size_t)(qd * 16 + t) * NPX + n0 + ln];
    short8 lo, hi;
#pragma unroll
    for (int t = 0; t < 8; ++t) { lo[t] = f2h(vb[t]); hi[t] = f2h(vb[8 + t]); }
    *reinterpret_cast<short8*>(&X[ln * 72 + qd * 16]) = lo;
    *reinterpret_cast<short8*>(&X[ln * 72 + qd * 16 + 8]) = hi;
}

// ---------------------------------------------------------------------------
// k_prep: transposed fp16 weights WT[e][k] + packed float biases
// fbias: [0..63] = ba|bbv merged per j ; [64..191] = bk|bv merged
// ---------------------------------------------------------------------------
__global__ __launch_bounds__(256) void k_prep(const float* __restrict__ wa,
                                              const float* __restrict__ wb,
                                              const float* __restrict__ in_w,
                                              const float* __restrict__ w1,
                                              const float* __restrict__ w2,
                                              const float* __restrict__ w3,
                                              const float* __restrict__ wq,
                                              const float* __restrict__ wk,
                                              const float* __restrict__ wv,
                                              const float* __restrict__ ba,
                                              const float* __restrict__ bbv,
                                              const float* __restrict__ bk,
                                              const float* __restrict__ bv,
                                              short* __restrict__ wt,
                                              float* __restrict__ fbias)
{
    int idx = blockIdx.x * 256 + threadIdx.x;
    if (idx >= WTOT) {
        int i = idx - WTOT;
        if (i < 64)       fbias[i] = (i < 4) ? ba[i] : bbv[i - 4];
        else if (i < 192) fbias[i] = (i < 128) ? bk[i - 64] : bv[i - 128];
        return;
    }
    float v;
    if (idx < WINW) {
        int j = idx >> 6, c = idx & 63;
        v = (j < 4) ? wa[c * 4 + j] : wb[((j - 4) / 3) * 192 + c * 3 + ((j - 4) % 3)];
    } else if (idx < W1T) {
        int i = idx - WINW; v = in_w[(i & 63) * 64 + (i >> 6)];
    } else if (idx < W2T) {
        int i = idx - W1T; v = w1[(i & 63) * 128 + (i >> 6)];
    } else if (idx < W3T) {
        int i = idx - W2T; v = w2[(i & 127) * 128 + (i >> 7)];
    } else if (idx < WQT) {
        int i = idx - W3T; v = w3[(i & 127) * 64 + (i >> 7)];
    } else if (idx < WKV) {
        int i = idx - WQT; v = wq[(i & 63) * 64 + (i >> 6)];
    } else {
        int i = idx - WKV; int e = i >> 6, k = i & 63;
        v = (e < 64) ? wk[k * 64 + e] : wv[k * 64 + (e - 64)];
    }
    wt[idx] = f2h(v);
}

// ---------------------------------------------------------------------------
// k_main: x,sem -> v, xm, and per-wave gram/nsq partials (q,k never hit HBM).
// 16 px/wave, barrier-free, swapped-operand GEMMs, packed LDS stores.
// ---------------------------------------------------------------------------
__global__ __launch_bounds__(256) void k_main(const float* __restrict__ x,
                                              const float* __restrict__ sem,
                                              const float* __restrict__ fbias,
                                              const float* __restrict__ in_b,
                                              const float* __restrict__ b1,
                                              const float* __restrict__ g1,
                                              const float* __restrict__ be1,
                                              const float* __restrict__ b2,
                                              const float* __restrict__ g2,
                                              const float* __restrict__ be2,
                                              const float* __restrict__ b3,
                                              const float* __restrict__ bq,
                                              const short* __restrict__ wt,
                                              short* __restrict__ vout,
                                              short* __restrict__ xmout,
                                              float* __restrict__ gram,
                                              float* __restrict__ nsq)
{
    __shared__ short sX[4][1280];   // x tile [16][72]; later k gram tile [64][20]
    __shared__ short sF[4][1280];   // feat/y tile [16][72]; later q gram tile [64][20]
    __shared__ short sS[4][2176];   // 128-wide tile [16][136]; later xm/v [16][72]
    int tid = threadIdx.x, w = tid >> 6, lane = tid & 63;
    int ln = lane & 15, qd = lane >> 4, qd4 = qd * 4;
    int pw = blockIdx.x * 64 + w * 16;
    int b = pw >> 14, n0 = pw & (NPX - 1);
    const float* xb = x + (size_t)b * 64 * NPX;
    short* X = sX[w];
    short* F = sF[w];
    short* S = sS[w];

    stage_x16(xb, n0, X);

    // two independent gemms on X
    f32x4 ah1[8];
    acc_biasT<8>(ah1, b1);
    gemmT<64, 8>(X, 72, wt + W1T, ah1);
    f32x4 af[4];
    { f32x4 z = {0,0,0,0}; for (int t = 0; t < 4; ++t) af[t] = z; }
    gemmT<64, 4>(X, 72, wt + WAB, af);

    // feat epilogue: relu(sem[cls][px]) * acc + bias -> F [px][72]
    {
        const float* semb = sem + (size_t)b * 21 * NPX + n0 + ln;
#pragma unroll
        for (int t = 0; t < 4; ++t) {
            f32x4 fb = *(const f32x4*)(fbias + t * 16 + qd4);
            short4v pk;
#pragma unroll
            for (int r = 0; r < 4; ++r) {
                int j = t * 16 + qd4 + r;
                int cls = (j < 4) ? 0 : 1 + (j - 4) / 3;
                float sm = fmaxf(semb[(size_t)cls * NPX], 0.f);
                pk[r] = f2h(sm * af[t][r] + fb[r]);
            }
            *reinterpret_cast<short4v*>(&F[ln * 72 + t * 16 + qd4]) = pk;
        }
    }
    // h1 = lrelu(LN(..)) -> S
    ln_T<8>(ah1, g1, be1);
    dstoreT<8>(ah1, S, 136);

    // y = feat @ in_w ; h2 = h1 @ w2   (independent)
    f32x4 ay[4];
    acc_biasT<4>(ay, in_b);
    gemmT<64, 4>(F, 72, wt + WINW, ay);
    f32x4 ah2[8];
    acc_biasT<8>(ah2, b2);
    gemmT<128, 8>(S, 136, wt + W2T, ah2);
    dstoreT<4>(ay, F, 72);          // y -> F
    ln_T<8>(ah2, g2, be2);
    dstoreT<8>(ah2, S, 136);        // h2 -> S

    // kv = y @ [wk|wv] ; xm = h2 @ w3   (independent)
    f32x4 akv[8];
    acc_biasT<8>(akv, fbias + 64);
    gemmT<64, 8>(F, 72, wt + WKV, akv);
    f32x4 axm[4];
    acc_biasT<4>(axm, b3);
    gemmT<128, 4>(S, 136, wt + W3T, axm);

    // xm out (S reused), then q = xm @ wq
    dstoreT<4>(axm, S, 72);
    copyout16(S, 72, xmout + (size_t)pw * 64);
    f32x4 aq[4];
    acc_biasT<4>(aq, bq);
    gemmT<64, 4>(S, 72, wt + WQT, aq);

    // v out via S
    dstoreT<4>(akv + 4, S, 72);
    copyout16(S, 72, vout + (size_t)pw * 64);

    // q -> F d-major [ch][20]; k -> X d-major [ch][20]
#pragma unroll
    for (int t = 0; t < 4; ++t)
#pragma unroll
        for (int r = 0; r < 4; ++r) {
            int ch = t * 16 + qd4 + r;
            F[ch * 20 + ln] = f2h(aq[t][r]);
            X[ch * 20 + ln] = f2h(akv[t][r]);
        }

    // per-head gram/nsq partials over this wave's 16 px
    f32x4 aqk[4], aqq[4], akk[4];
#pragma unroll
    for (int h = 0; h < 4; ++h) {
        half4 qf = *(const half4*)(&F[(h * 16 + ln) * 20 + qd4]);
        half4 kf = *(const half4*)(&X[(h * 16 + ln) * 20 + qd4]);
        f32x4 z = {0,0,0,0};
        aqk[h] = mfmah16(qf, kf, z);
        aqq[h] = mfmah16(qf, qf, z);
        akk[h] = mfmah16(kf, kf, z);
    }
#pragma unroll
    for (int h = 0; h < 4; ++h) {
        int bh = b * 4 + h;
        int e = ln;
#pragma unroll
        for (int r = 0; r < 4; ++r) {
            int d = qd4 + r;
            atomicAdd(&gram[bh * 256 + d * 16 + e], aqk[h][r]);
            if (e == d) {
                atomicAdd(&nsq[bh * 16 + d], aqq[h][r]);
                atomicAdd(&nsq[256 + bh * 16 + d], akk[h][r]);
            }
        }
    }
}

// ---------------------------------------------------------------------------
// k_attnM: softmax + fold wo -> MT[b][cc][he] fp16
// ---------------------------------------------------------------------------
__global__ __launch_bounds__(256) void k_attnM(const float* __restrict__ gram,
                                               const float* __restrict__ nsq,
                                               const float* __restrict__ rescale,
                                               const float* __restrict__ wo,
                                               short* __restrict__ MT)
{
    __shared__ float s_at[1024];
    int b = blockIdx.x, tid = threadIdx.x;
    if (tid < 64) {
        int h = tid >> 4, d = tid & 15;
        float nq = sqrtf(nsq[b * 64 + h * 16 + d]) + 1e-8f;
        float rsc = rescale[h];
        float lg[16];
#pragma unroll
        for (int e = 0; e < 16; ++e) {
            float nk = sqrtf(nsq[256 + b * 64 + h * 16 + e]) + 1e-8f;
            lg[e] = rsc * gram[b * 1024 + h * 256 + d * 16 + e] / (nq * nk);
        }
        float m = lg[0];
#pragma unroll
        for (int e = 1; e < 16; ++e) m = fmaxf(m, lg[e]);
        float ssum = 0.f;
#pragma unroll
        for (int e = 0; e < 16; ++e) { lg[e] = expf(lg[e] - m); ssum += lg[e]; }
        float inv = 1.f / ssum;
#pragma unroll
        for (int e = 0; e < 16; ++e) s_at[h * 256 + d * 16 + e] = lg[e] * inv;
    }
    __syncthreads();
    int he = tid >> 2, h = he >> 4, e = he & 15;
    int cc0 = (tid & 3) * 16;
#pragma unroll
    for (int cx = 0; cx < 16; ++cx) {
        int cc = cc0 + cx;
        float s = 0.f;
#pragma unroll
        for (int d = 0; d < 16; ++d)
            s = fmaf(s_at[h * 256 + d * 16 + e], wo[(h * 16 + d) * 64 + cc], s);
        MT[b * 4096 + cc * 64 + he] = f2h(s);
    }
}

// ---------------------------------------------------------------------------
// k_out: out[b][c][n] = v@M + bo + xm   (unswapped: px in regs -> f32x4 writes)
// ---------------------------------------------------------------------------
__global__ __launch_bounds__(256) void k_out(const short* __restrict__ v,
                                             const short* __restrict__ xm,
                                             const short* __restrict__ MT,
                                             const float* __restrict__ bo,
                                             float* __restrict__ out)
{
    int tid = threadIdx.x, w = tid >> 6, lane = tid & 63;
    int ln = lane & 15, qd = lane >> 4;
    int pw = blockIdx.x * 64 + w * 16;
    int b = pw >> 14, n0 = pw & (NPX - 1);

    f32x4 acc[4];
    {
#pragma unroll
        for (int t = 0; t < 4; ++t) {
            float bv = bo[t * 16 + ln];
            f32x4 vv = {bv, bv, bv, bv};
            acc[t] = vv;
        }
    }
    // A-op = v tile rows (px), B-op = MT
    {
        const short* ap = v + (size_t)pw * 64;
        const short* bp = MT + b * 4096 + ln * 64 + ((lane >> 4) * 8);
#pragma unroll
        for (int c0 = 0; c0 < 64; c0 += 32) {
            half8 a = *(const half8*)(ap + (size_t)ln * 64 + ((lane >> 4) * 8) + c0);
#pragma unroll
            for (int t = 0; t < 4; ++t) {
                half8 bb = *(const half8*)(bp + (size_t)t * 16 * 64 + c0);
                acc[t] = mfmah(a, bb, acc[t]);
            }
        }
    }
#pragma unroll
    for (int t = 0; t < 4; ++t) {
        int c = t * 16 + ln;
        f32x4 o;
#pragma unroll
        for (int r = 0; r < 4; ++r)
            o[r] = acc[t][r] + h2f(xm[(size_t)(pw + qd * 4 + r) * 64 + c]);
        *reinterpret_cast<f32x4*>(out + ((size_t)b * 64 + c) * NPX + n0 + qd * 4) = o;
    }
}

// ---------------------------------------------------------------------------
extern "C" void kernel_launch(void* const* d_in, const int* in_sizes, int n_in,
                              void* d_out, int out_size, void* d_ws, size_t ws_size,
                              hipStream_t stream)
{
    const float* x    = (const float*)d_in[0];
    const float* sem  = (const float*)d_in[1];
    const float* wa   = (const float*)d_in[2];
    const float* ba   = (const float*)d_in[3];
    const float* wb   = (const float*)d_in[4];
    const float* bbv  = (const float*)d_in[5];
    const float* in_w = (const float*)d_in[6];
    const float* in_b = (const float*)d_in[7];
    const float* w1   = (const float*)d_in[8];
    const float* b1   = (const float*)d_in[9];
    const float* g1   = (const float*)d_in[10];
    const float* be1  = (const float*)d_in[11];
    const float* w2   = (const float*)d_in[12];
    const float* b2   = (const float*)d_in[13];
    const float* g2   = (const float*)d_in[14];
    const float* be2  = (const float*)d_in[15];
    const float* w3   = (const float*)d_in[16];
    const float* b3   = (const float*)d_in[17];
    const float* wq   = (const float*)d_in[18];
    const float* bq   = (const float*)d_in[19];
    const float* wk   = (const float*)d_in[20];
    const float* bk   = (const float*)d_in[21];
    const float* wv   = (const float*)d_in[22];
    const float* bv   = (const float*)d_in[23];
    const float* wo   = (const float*)d_in[24];
    const float* bo   = (const float*)d_in[25];
    const float* rescale = (const float*)d_in[26];

    char* wsb = (char*)d_ws;
    short* wt    = (short*)wsb;                                // 53248 shorts
    float* fbias = (float*)(wsb + (128u << 10));               // 192 f32
    short* vpx   = (short*)(wsb + (1u << 20));                 // 8 MB [n][64] fp16
    short* xmp   = (short*)(wsb + (1u << 20) + (8u << 20));    // 8 MB
    float* gram  = (float*)(wsb + (1u << 20) + (16u << 20));   // 4096 f32
    float* nsq   = gram + 4096;                                // 512 f32
    short* MT    = (short*)(nsq + 512);                        // 16384 shorts

    dim3 blk(256);
    k_prep<<<dim3(209), blk, 0, stream>>>(wa, wb, in_w, w1, w2, w3, wq, wk, wv,
                                          ba, bbv, bk, bv, wt, fbias);
    hipMemsetAsync(gram, 0, (4096 + 512) * sizeof(float), stream);
    k_main<<<dim3(1024), blk, 0, stream>>>(x, sem, fbias, in_b,
                                           b1, g1, be1, b2, g2, be2, b3, bq,
                                           wt, vpx, xmp, gram, nsq);
    k_attnM<<<dim3(4), blk, 0, stream>>>(gram, nsq, rescale, wo, MT);
    k_out<<<dim3(1024), blk, 0, stream>>>(vpx, xmp, MT, bo, (float*)d_out);
}

// Round 9
// 267.271 us; speedup vs baseline: 1.3451x; 1.3451x over previous
//
#include <hip/hip_runtime.h>
#include <hip/hip_bf16.h>

#define NPX 16384
typedef __attribute__((ext_vector_type(8))) short short8;
typedef __attribute__((ext_vector_type(4))) short short4v;
typedef __attribute__((ext_vector_type(8))) _Float16 half8;
typedef __attribute__((ext_vector_type(4))) _Float16 half4;
typedef __attribute__((ext_vector_type(4))) float f32x4;

#define DEV static __device__ __forceinline__

// wt layout (fp16 shorts)
#define WAB   0
#define WINW  4096
#define W1T   8192
#define W2T   16384
#define W3T   32768
#define WQT   40960
#define WKV   45056
#define WTOT  53248

// per-block gram partial: [4 heads][16][16] + nsq_q[64] + nsq_k[64]
#define PART_N 1152

DEV float lrelu(float v) { return v >= 0.f ? v : 0.01f * v; }
DEV short f2h(float f) { _Float16 h = (_Float16)f; return __builtin_bit_cast(short, h); }
DEV float h2f(short s) { return (float)__builtin_bit_cast(_Float16, s); }
DEV f32x4 mfmah(half8 a, half8 b, f32x4 c) {
    return __builtin_amdgcn_mfma_f32_16x16x32_f16(a, b, c, 0, 0, 0);
}
DEV f32x4 mfmah16(half4 a, half4 b, f32x4 c) {
    return __builtin_amdgcn_mfma_f32_16x16x16f16(a, b, c, 0, 0, 0);
}

// ---------------------------------------------------------------------------
// Swapped-operand GEMM: acc[t] = W(A-op) x tile(B-op).
// D: lane ln -> px=ln ; reg r of tile t -> channel e = t*16 + (lane>>4)*4 + r
// ---------------------------------------------------------------------------
template<int K, int NT>
DEV void gemmT(const short* __restrict__ A, int pitch,
               const short* __restrict__ WT, f32x4 (&acc)[NT])
{
    int lane = threadIdx.x & 63;
    int ln = lane & 15, q8 = (lane >> 4) * 8;
    const short* bp = A + (size_t)ln * pitch + q8;
#pragma unroll
    for (int c0 = 0; c0 < K; c0 += 32) {
        half8 bfrag = *(const half8*)(bp + c0);
#pragma unroll
        for (int t = 0; t < NT; ++t) {
            half8 afrag = *(const half8*)(WT + (size_t)(t * 16 + ln) * K + q8 + c0);
            acc[t] = mfmah(afrag, bfrag, acc[t]);
        }
    }
}

template<int NT>
DEV void acc_biasT(f32x4 (&acc)[NT], const float* __restrict__ bias)
{
    int qd4 = ((threadIdx.x & 63) >> 4) * 4;
#pragma unroll
    for (int t = 0; t < NT; ++t) acc[t] = *(const f32x4*)(bias + t * 16 + qd4);
}

// packed b64 store of D into [px][ch] tile
template<int NT>
DEV void dstoreT(const f32x4* acc, short* sD, int pitch)
{
    int lane = threadIdx.x & 63;
    int ln = lane & 15, qd4 = (lane >> 4) * 4;
#pragma unroll
    for (int t = 0; t < NT; ++t) {
        short4v pk = {f2h(acc[t][0]), f2h(acc[t][1]), f2h(acc[t][2]), f2h(acc[t][3])};
        *reinterpret_cast<short4v*>(&sD[ln * pitch + t * 16 + qd4]) = pk;
    }
}

// in-register LayerNorm(+lrelu) over 128 ch (per px=ln); 2 shuffles
template<int NT>
DEV void ln_T(f32x4 (&acc)[NT], const float* __restrict__ g, const float* __restrict__ be)
{
    int qd4 = ((threadIdx.x & 63) >> 4) * 4;
    float s = 0.f, ss = 0.f;
#pragma unroll
    for (int t = 0; t < NT; ++t)
#pragma unroll
        for (int r = 0; r < 4; ++r) { float v = acc[t][r]; s += v; ss += v * v; }
    s += __shfl_xor(s, 16); ss += __shfl_xor(ss, 16);
    s += __shfl_xor(s, 32); ss += __shfl_xor(ss, 32);
    float m = s * (1.f / 128.f);
    float var = ss * (1.f / 128.f) - m * m;
    float rs = rsqrtf(var + 1e-5f);
#pragma unroll
    for (int t = 0; t < NT; ++t) {
        f32x4 gg = *(const f32x4*)(g + t * 16 + qd4);
        f32x4 bb = *(const f32x4*)(be + t * 16 + qd4);
#pragma unroll
        for (int r = 0; r < 4; ++r)
            acc[t][r] = lrelu((acc[t][r] - m) * rs * gg[r] + bb[r]);
    }
}

// wave-level copyout of 16x64 fp16 tile -> global [px][64]
DEV void copyout16(const short* sD, int pitch, short* __restrict__ dst)
{
    int lane = threadIdx.x & 63;
#pragma unroll
    for (int it = 0; it < 2; ++it) {
        int idx = it * 512 + lane * 8;
        int px = idx >> 6, c = idx & 63;
        short8 v = *(const short8*)(&sD[px * pitch + c]);
        *reinterpret_cast<short8*>(dst + (size_t)px * 64 + c) = v;
    }
}

// stage 16 px of x (fp32 channel-major) -> wave LDS [16][72] fp16
DEV void stage_x16(const float* __restrict__ xb, int n0, short* X)
{
    int lane = threadIdx.x & 63;
    int ln = lane & 15, qd = lane >> 4;
    float vb[16];
#pragma unroll
    for (int t = 0; t < 16; ++t) vb[t] = xb[(size_t)(qd * 16 + t) * NPX + n0 + ln];
    short8 lo, hi;
#pragma unroll
    for (int t = 0; t < 8; ++t) { lo[t] = f2h(vb[t]); hi[t] = f2h(vb[8 + t]); }
    *reinterpret_cast<short8*>(&X[ln * 72 + qd * 16]) = lo;
    *reinterpret_cast<short8*>(&X[ln * 72 + qd * 16 + 8]) = hi;
}

// ---------------------------------------------------------------------------
// k_prep: transposed fp16 weights WT[e][k] + packed float biases
// ---------------------------------------------------------------------------
__global__ __launch_bounds__(256) void k_prep(const float* __restrict__ wa,
                                              const float* __restrict__ wb,
                                              const float* __restrict__ in_w,
                                              const float* __restrict__ w1,
                                              const float* __restrict__ w2,
                                              const float* __restrict__ w3,
                                              const float* __restrict__ wq,
                                              const float* __restrict__ wk,
                                              const float* __restrict__ wv,
                                              const float* __restrict__ ba,
                                              const float* __restrict__ bbv,
                                              const float* __restrict__ bk,
                                              const float* __restrict__ bv,
                                              short* __restrict__ wt,
                                              float* __restrict__ fbias)
{
    int idx = blockIdx.x * 256 + threadIdx.x;
    if (idx >= WTOT) {
        int i = idx - WTOT;
        if (i < 64)       fbias[i] = (i < 4) ? ba[i] : bbv[i - 4];
        else if (i < 192) fbias[i] = (i < 128) ? bk[i - 64] : bv[i - 128];
        return;
    }
    float v;
    if (idx < WINW) {
        int j = idx >> 6, c = idx & 63;
        v = (j < 4) ? wa[c * 4 + j] : wb[((j - 4) / 3) * 192 + c * 3 + ((j - 4) % 3)];
    } else if (idx < W1T) {
        int i = idx - WINW; v = in_w[(i & 63) * 64 + (i >> 6)];
    } else if (idx < W2T) {
        int i = idx - W1T; v = w1[(i & 63) * 128 + (i >> 6)];
    } else if (idx < W3T) {
        int i = idx - W2T; v = w2[(i & 127) * 128 + (i >> 7)];
    } else if (idx < WQT) {
        int i = idx - W3T; v = w3[(i & 127) * 64 + (i >> 7)];
    } else if (idx < WKV) {
        int i = idx - WQT; v = wq[(i & 63) * 64 + (i >> 6)];
    } else {
        int i = idx - WKV; int e = i >> 6, k = i & 63;
        v = (e < 64) ? wk[k * 64 + e] : wv[k * 64 + (e - 64)];
    }
    wt[idx] = f2h(v);
}

// ---------------------------------------------------------------------------
// k_main: x,sem -> v, xm ; gram/nsq partials via LDS block-reduce -> unique
// global slot per block (NO global atomics). 16 px/wave, swapped GEMMs.
// ---------------------------------------------------------------------------
__global__ __launch_bounds__(256, 4) void k_main(const float* __restrict__ x,
                                                 const float* __restrict__ sem,
                                                 const float* __restrict__ fbias,
                                                 const float* __restrict__ in_b,
                                                 const float* __restrict__ b1,
                                                 const float* __restrict__ g1,
                                                 const float* __restrict__ be1,
                                                 const float* __restrict__ b2,
                                                 const float* __restrict__ g2,
                                                 const float* __restrict__ be2,
                                                 const float* __restrict__ b3,
                                                 const float* __restrict__ bq,
                                                 const short* __restrict__ wt,
                                                 short* __restrict__ vout,
                                                 short* __restrict__ xmout,
                                                 float* __restrict__ part)
{
    __shared__ short sB1[4][1280];   // [16][72] px tile  OR  [64][20] d-major q
    __shared__ short sS[4][2176];    // [16][136] tile    OR  [64][20] d-major k
    __shared__ float s_gr[PART_N];   // block gram+nsq accumulator
    int tid = threadIdx.x, w = tid >> 6, lane = tid & 63;
    int ln = lane & 15, qd = lane >> 4, qd4 = qd * 4;

    for (int i = tid; i < PART_N; i += 256) s_gr[i] = 0.f;
    __syncthreads();

    int pw = blockIdx.x * 64 + w * 16;
    int b = pw >> 14, n0 = pw & (NPX - 1);
    const float* xb = x + (size_t)b * 64 * NPX;
    short* B1 = sB1[w];
    short* S  = sS[w];

    stage_x16(xb, n0, B1);

    // two independent gemms on x-tile
    f32x4 ah1[8];
    acc_biasT<8>(ah1, b1);
    gemmT<64, 8>(B1, 72, wt + W1T, ah1);
    f32x4 af[4];
    { f32x4 z = {0,0,0,0}; for (int t = 0; t < 4; ++t) af[t] = z; }
    gemmT<64, 4>(B1, 72, wt + WAB, af);

    // feat epilogue -> B1 (x dead)
    {
        const float* semb = sem + (size_t)b * 21 * NPX + n0 + ln;
#pragma unroll
        for (int t = 0; t < 4; ++t) {
            f32x4 fb = *(const f32x4*)(fbias + t * 16 + qd4);
            short4v pk;
#pragma unroll
            for (int r = 0; r < 4; ++r) {
                int j = t * 16 + qd4 + r;
                int cls = (j < 4) ? 0 : 1 + (j - 4) / 3;
                float sm = fmaxf(semb[(size_t)cls * NPX], 0.f);
                pk[r] = f2h(sm * af[t][r] + fb[r]);
            }
            *reinterpret_cast<short4v*>(&B1[ln * 72 + t * 16 + qd4]) = pk;
        }
    }
    // h1 -> S
    ln_T<8>(ah1, g1, be1);
    dstoreT<8>(ah1, S, 136);

    // y = feat @ in_w ; h2 = h1 @ w2
    f32x4 ay[4];
    acc_biasT<4>(ay, in_b);
    gemmT<64, 4>(B1, 72, wt + WINW, ay);
    f32x4 ah2[8];
    acc_biasT<8>(ah2, b2);
    gemmT<128, 8>(S, 136, wt + W2T, ah2);
    dstoreT<4>(ay, B1, 72);            // y -> B1
    ln_T<8>(ah2, g2, be2);
    dstoreT<8>(ah2, S, 136);           // h2 -> S

    // kv = y @ [wk|wv]
    f32x4 akv[8];
    acc_biasT<8>(akv, fbias + 64);
    gemmT<64, 8>(B1, 72, wt + WKV, akv);
    // v out via B1 (y dead)
    dstoreT<4>(akv + 4, B1, 72);
    copyout16(B1, 72, vout + (size_t)pw * 64);

    // xm = h2 @ w3
    f32x4 axm[4];
    acc_biasT<4>(axm, b3);
    gemmT<128, 4>(S, 136, wt + W3T, axm);
    dstoreT<4>(axm, B1, 72);
    copyout16(B1, 72, xmout + (size_t)pw * 64);

    // q = xm @ wq (reads B1 = xm tile)
    f32x4 aq[4];
    acc_biasT<4>(aq, bq);
    gemmT<64, 4>(B1, 72, wt + WQT, aq);

    // d-major tiles: q -> B1 [64][20], k -> S [64][20]
#pragma unroll
    for (int t = 0; t < 4; ++t)
#pragma unroll
        for (int r = 0; r < 4; ++r) {
            int ch = t * 16 + qd4 + r;
            B1[ch * 20 + ln] = f2h(aq[t][r]);
            S[ch * 20 + ln]  = f2h(akv[t][r]);
        }

    // per-head gram/nsq over this wave's 16 px -> LDS accumulate
#pragma unroll
    for (int h = 0; h < 4; ++h) {
        half4 qf = *(const half4*)(&B1[(h * 16 + ln) * 20 + qd4]);
        half4 kf = *(const half4*)(&S[(h * 16 + ln) * 20 + qd4]);
        f32x4 z = {0,0,0,0};
        f32x4 aqk = mfmah16(qf, kf, z);
        f32x4 aqq = mfmah16(qf, qf, z);
        f32x4 akk = mfmah16(kf, kf, z);
#pragma unroll
        for (int r = 0; r < 4; ++r) {
            int d = qd4 + r;
            atomicAdd(&s_gr[h * 256 + d * 16 + ln], aqk[r]);
            if (ln == d) {
                atomicAdd(&s_gr[1024 + h * 16 + d], aqq[r]);
                atomicAdd(&s_gr[1088 + h * 16 + d], akk[r]);
            }
        }
    }
    __syncthreads();
    // one unique slot per block: plain coalesced stores, no atomics
    float* pp = part + (size_t)blockIdx.x * PART_N;
    for (int i = tid; i < PART_N; i += 256) pp[i] = s_gr[i];
}

// ---------------------------------------------------------------------------
// k_attnM: reduce 256 block-partials per batch, softmax, fold wo -> MT fp16
// ---------------------------------------------------------------------------
__global__ __launch_bounds__(256) void k_attnM(const float* __restrict__ part,
                                               const float* __restrict__ rescale,
                                               const float* __restrict__ wo,
                                               short* __restrict__ MT)
{
    __shared__ float s_gr[PART_N];
    __shared__ float s_at[1024];
    int b = blockIdx.x, tid = threadIdx.x;
    for (int idx = tid; idx < PART_N; idx += 256) {
        float s = 0.f;
        const float* p = part + ((size_t)b * 256) * PART_N + idx;
        for (int sl = 0; sl < 256; ++sl) s += p[(size_t)sl * PART_N];
        s_gr[idx] = s;
    }
    __syncthreads();
    if (tid < 64) {
        int h = tid >> 4, d = tid & 15;
        float nq = sqrtf(s_gr[1024 + h * 16 + d]) + 1e-8f;
        float rsc = rescale[h];
        float lg[16];
#pragma unroll
        for (int e = 0; e < 16; ++e) {
            float nk = sqrtf(s_gr[1088 + h * 16 + e]) + 1e-8f;
            lg[e] = rsc * s_gr[h * 256 + d * 16 + e] / (nq * nk);
        }
        float m = lg[0];
#pragma unroll
        for (int e = 1; e < 16; ++e) m = fmaxf(m, lg[e]);
        float ssum = 0.f;
#pragma unroll
        for (int e = 0; e < 16; ++e) { lg[e] = expf(lg[e] - m); ssum += lg[e]; }
        float inv = 1.f / ssum;
#pragma unroll
        for (int e = 0; e < 16; ++e) s_at[h * 256 + d * 16 + e] = lg[e] * inv;
    }
    __syncthreads();
    int he = tid >> 2, h = he >> 4, e = he & 15;
    int cc0 = (tid & 3) * 16;
#pragma unroll
    for (int cx = 0; cx < 16; ++cx) {
        int cc = cc0 + cx;
        float s = 0.f;
#pragma unroll
        for (int d = 0; d < 16; ++d)
            s = fmaf(s_at[h * 256 + d * 16 + e], wo[(h * 16 + d) * 64 + cc], s);
        MT[b * 4096 + cc * 64 + he] = f2h(s);
    }
}

// ---------------------------------------------------------------------------
// k_out: out[b][c][n] = v@M + bo + xm   (px-in-regs orientation, f32x4 writes)
// ---------------------------------------------------------------------------
__global__ __launch_bounds__(256) void k_out(const short* __restrict__ v,
                                             const short* __restrict__ xm,
                                             const short* __restrict__ MT,
                                             const float* __restrict__ bo,
                                             float* __restrict__ out)
{
    int tid = threadIdx.x, w = tid >> 6, lane = tid & 63;
    int ln = lane & 15, qd = lane >> 4;
    int pw = blockIdx.x * 64 + w * 16;
    int b = pw >> 14, n0 = pw & (NPX - 1);

    f32x4 acc[4];
#pragma unroll
    for (int t = 0; t < 4; ++t) {
        float bv = bo[t * 16 + ln];
        f32x4 vv = {bv, bv, bv, bv};
        acc[t] = vv;
    }
    {
        const short* ap = v + (size_t)pw * 64;
        const short* bp = MT + b * 4096 + ln * 64 + ((lane >> 4) * 8);
#pragma unroll
        for (int c0 = 0; c0 < 64; c0 += 32) {
            half8 a = *(const half8*)(ap + (size_t)ln * 64 + ((lane >> 4) * 8) + c0);
#pragma unroll
            for (int t = 0; t < 4; ++t) {
                half8 bb = *(const half8*)(bp + (size_t)t * 16 * 64 + c0);
                acc[t] = mfmah(a, bb, acc[t]);
            }
        }
    }
#pragma unroll
    for (int t = 0; t < 4; ++t) {
        int c = t * 16 + ln;
        f32x4 o;
#pragma unroll
        for (int r = 0; r < 4; ++r)
            o[r] = acc[t][r] + h2f(xm[(size_t)(pw + qd * 4 + r) * 64 + c]);
        *reinterpret_cast<f32x4*>(out + ((size_t)b * 64 + c) * NPX + n0 + qd * 4) = o;
    }
}

// ---------------------------------------------------------------------------
extern "C" void kernel_launch(void* const* d_in, const int* in_sizes, int n_in,
                              void* d_out, int out_size, void* d_ws, size_t ws_size,
                              hipStream_t stream)
{
    const float* x    = (const float*)d_in[0];
    const float* sem  = (const float*)d_in[1];
    const float* wa   = (const float*)d_in[2];
    const float* ba   = (const float*)d_in[3];
    const float* wb   = (const float*)d_in[4];
    const float* bbv  = (const float*)d_in[5];
    const float* in_w = (const float*)d_in[6];
    const float* in_b = (const float*)d_in[7];
    const float* w1   = (const float*)d_in[8];
    const float* b1   = (const float*)d_in[9];
    const float* g1   = (const float*)d_in[10];
    const float* be1  = (const float*)d_in[11];
    const float* w2   = (const float*)d_in[12];
    const float* b2   = (const float*)d_in[13];
    const float* g2   = (const float*)d_in[14];
    const float* be2  = (const float*)d_in[15];
    const float* w3   = (const float*)d_in[16];
    const float* b3   = (const float*)d_in[17];
    const float* wq   = (const float*)d_in[18];
    const float* bq   = (const float*)d_in[19];
    const float* wk   = (const float*)d_in[20];
    const float* bk   = (const float*)d_in[21];
    const float* wv   = (const float*)d_in[22];
    const float* bv   = (const float*)d_in[23];
    const float* wo   = (const float*)d_in[24];
    const float* bo   = (const float*)d_in[25];
    const float* rescale = (const float*)d_in[26];

    char* wsb = (char*)d_ws;
    short* wt    = (short*)wsb;                                // 53248 shorts
    float* fbias = (float*)(wsb + (128u << 10));               // 192 f32
    short* vpx   = (short*)(wsb + (1u << 20));                 // 8 MB [n][64] fp16
    short* xmp   = (short*)(wsb + (1u << 20) + (8u << 20));    // 8 MB
    float* part  = (float*)(wsb + (1u << 20) + (16u << 20));   // 1024*1152 f32 ~4.7MB
    short* MT    = (short*)(wsb + (1u << 20) + (22u << 20));   // 16384 shorts

    dim3 blk(256);
    k_prep<<<dim3(209), blk, 0, stream>>>(wa, wb, in_w, w1, w2, w3, wq, wk, wv,
                                          ba, bbv, bk, bv, wt, fbias);
    k_main<<<dim3(1024), blk, 0, stream>>>(x, sem, fbias, in_b,
                                           b1, g1, be1, b2, g2, be2, b3, bq,
                                           wt, vpx, xmp, part);
    k_attnM<<<dim3(4), blk, 0, stream>>>(part, rescale, wo, MT);
    k_out<<<dim3(1024), blk, 0, stream>>>(vpx, xmp, MT, bo, (float*)d_out);
}